// Round 17
// baseline (443.555 us; speedup 1.0000x reference)
//
#include <hip/hip_runtime.h>

// etp: out[n, coff(l3)+m3, u] = sum_p sum_{m1,m2} cg_p[m1,m2,m3] * Y[n, yoff(l1)+m1]
//                               * H[n, coff(l2)+m2, u] * W[n, p, u]
// N=16384 edges, 16 ch (l=0..3, dims 1,3,5,7), MUL=128.
//
// R16: one wave per edge, each lane owns u=2l and u=2l+1 as TWO INDEPENDENT
// SCALAR streams (acc0/acc1, h0/h1, w0/w1 — no ext-vector types in the
// register file; f2/f4 aligned-pair pressure caused the R10/R14 spills).
// Halves the per-edge wave count vs R13 (B-broadcast ds_read_b128 total
// and instruction issue both scale with waves), HBM bytes unchanged.
// Kept: R11 build, l2-grouped short live ranges, R13-style sequential
// scalar pins, launch_bounds(256,6) (85-VGPR cap), nontemporal stores.

#define BS 256
#define EPB 4     // edges per block (one wave each)
#define YD 16
#define HD 2048
#define WD 2944
#define NROW 99   // sum of d3 over paths (B rows, padded to 8 floats)

typedef float f4 __attribute__((ext_vector_type(4)));  // LDS reads only

// X(p, l1, l2, l3, cg_offset, row_offset) — build phase
#define FOR_PATHS(X) \
  X(0, 0,0,0,    0,  0) \
  X(1, 0,1,1,    1,  1) \
  X(2, 0,2,2,   10,  4) \
  X(3, 0,3,3,   35,  9) \
  X(4, 1,0,1,   84, 16) \
  X(5, 1,1,0,   93, 19) \
  X(6, 1,1,2,  102, 20) \
  X(7, 1,2,1,  147, 25) \
  X(8, 1,2,3,  192, 28) \
  X(9, 1,3,2,  297, 35) \
  X(10,2,0,2,  402, 40) \
  X(11,2,1,1,  427, 45) \
  X(12,2,1,3,  472, 48) \
  X(13,2,2,0,  577, 55) \
  X(14,2,2,2,  602, 56) \
  X(15,2,3,1,  727, 61) \
  X(16,2,3,3,  832, 64) \
  X(17,3,0,3, 1077, 71) \
  X(18,3,1,2, 1126, 78) \
  X(19,3,2,1, 1231, 83) \
  X(20,3,2,3, 1336, 86) \
  X(21,3,3,0, 1581, 93) \
  X(22,3,3,2, 1630, 94)

__host__ __device__ constexpr int coff(int l) {
  return l == 0 ? 0 : (l == 1 ? 1 : (l == 2 ? 4 : 9));
}

__global__ __launch_bounds__(BS, 6) void etp_kernel(
    const float* __restrict__ Y, const float* __restrict__ H,
    const float* __restrict__ W, const float* __restrict__ CG,
    float* __restrict__ O) {
  const int g = threadIdx.x >> 6;   // edge within block
  const int l = threadIdx.x & 63;   // lane; owns u = 2l and 2l+1
  const size_t n = (size_t)blockIdx.x * EPB + g;

  __shared__ __align__(16) float Bsm[EPB][NROW * 8];  // 12672 B
  __shared__ float ysm[EPB][YD];

  { const int t = threadIdx.x;
    if (t < EPB * YD) {
      const int e = t >> 4, c = t & 15;
      ysm[e][c] = Y[(size_t)(blockIdx.x * EPB + e) * YD + c];
    } }
  __syncthreads();

  // Phase 1: B_p[m3][m2] = sum_a cg_p[a,m2,m3] * y[coff(l1)+a]; d2*d3<=49<64.
#define BUILD(P, L1, L2, L3, CGO, RO) { \
    constexpr int d1 = 2*(L1)+1, d2 = 2*(L2)+1, d3 = 2*(L3)+1; \
    if (l < d2 * d3) { \
      const int m3 = l / d2, m2 = l - m3 * d2; \
      float s = 0.f; \
      _Pragma("unroll") \
      for (int a = 0; a < d1; ++a) \
        s += CG[(CGO) + (a * d2 + m2) * d3 + m3] * ysm[g][coff(L1) + a]; \
      Bsm[g][((RO) + m3) * 8 + m2] = s; \
    } }
  FOR_PATHS(BUILD)
#undef BUILD
  __syncthreads();

  // Phase 2: two scalar u-streams per lane; l2-grouped; burst+pin per group.
  const float* __restrict__ Hn = H + n * HD + 2 * l;
  const float* __restrict__ Wn = W + n * WD + 2 * l;
  float* __restrict__ On = O + n * HD + 2 * l;

  float acc0[YD], acc1[YD];
#pragma unroll
  for (int c = 0; c < YD; ++c) { acc0[c] = 0.f; acc1[c] = 0.f; }

#define PIN(x) asm volatile("" : "+v"(x));

#define DOP(WI, L2V, L3V, RO) { \
    constexpr int d2 = 2*(L2V)+1, d3 = 2*(L3V)+1; \
    const float wv0 = w0[WI], wv1 = w1[WI]; \
    _Pragma("unroll") \
    for (int m3 = 0; m3 < d3; ++m3) { \
      const f4* row = (const f4*)&Bsm[g][((RO) + m3) * 8]; \
      float br[8]; \
      *(f4*)&br[0] = row[0]; \
      if (d2 > 4) *(f4*)&br[4] = row[1]; \
      float s0 = 0.f, s1 = 0.f; \
      _Pragma("unroll") \
      for (int m2 = 0; m2 < d2; ++m2) { \
        s0 += br[m2] * h0[m2]; s1 += br[m2] * h1[m2]; \
      } \
      acc0[coff(L3V) + m3] += s0 * wv0; \
      acc1[coff(L3V) + m3] += s1 * wv1; \
    } }

  { // l2=0: paths 0,4,10,17
    float h0[1], h1[1], w0[4], w1[4];
    h0[0] = Hn[0]; h1[0] = Hn[1];
    w0[0] = Wn[0 * 128];  w1[0] = Wn[0 * 128 + 1];
    w0[1] = Wn[4 * 128];  w1[1] = Wn[4 * 128 + 1];
    w0[2] = Wn[10 * 128]; w1[2] = Wn[10 * 128 + 1];
    w0[3] = Wn[17 * 128]; w1[3] = Wn[17 * 128 + 1];
    PIN(h0[0]) PIN(h1[0])
    PIN(w0[0]) PIN(w1[0]) PIN(w0[1]) PIN(w1[1])
    PIN(w0[2]) PIN(w1[2]) PIN(w0[3]) PIN(w1[3])
    DOP(0, 0, 0, 0)  DOP(1, 0, 1, 16)  DOP(2, 0, 2, 40)  DOP(3, 0, 3, 71)
  }
  { // l2=1: paths 1,5,6,11,12,18
    float h0[3], h1[3], w0[6], w1[6];
#pragma unroll
    for (int m = 0; m < 3; ++m) {
      h0[m] = Hn[(1 + m) * 128]; h1[m] = Hn[(1 + m) * 128 + 1];
    }
    const int pid[6] = {1, 5, 6, 11, 12, 18};
#pragma unroll
    for (int i = 0; i < 6; ++i) {
      w0[i] = Wn[pid[i] * 128]; w1[i] = Wn[pid[i] * 128 + 1];
    }
#pragma unroll
    for (int m = 0; m < 3; ++m) { PIN(h0[m]) PIN(h1[m]) }
#pragma unroll
    for (int i = 0; i < 6; ++i) { PIN(w0[i]) PIN(w1[i]) }
    DOP(0, 1, 1, 1)   DOP(1, 1, 0, 19)  DOP(2, 1, 2, 20)
    DOP(3, 1, 1, 45)  DOP(4, 1, 3, 48)  DOP(5, 1, 2, 78)
  }
  { // l2=2: paths 2,7,8,13,14,19,20
    float h0[5], h1[5], w0[7], w1[7];
#pragma unroll
    for (int m = 0; m < 5; ++m) {
      h0[m] = Hn[(4 + m) * 128]; h1[m] = Hn[(4 + m) * 128 + 1];
    }
    const int pid[7] = {2, 7, 8, 13, 14, 19, 20};
#pragma unroll
    for (int i = 0; i < 7; ++i) {
      w0[i] = Wn[pid[i] * 128]; w1[i] = Wn[pid[i] * 128 + 1];
    }
#pragma unroll
    for (int m = 0; m < 5; ++m) { PIN(h0[m]) PIN(h1[m]) }
#pragma unroll
    for (int i = 0; i < 7; ++i) { PIN(w0[i]) PIN(w1[i]) }
    DOP(0, 2, 2, 4)   DOP(1, 2, 1, 25)  DOP(2, 2, 3, 28)
    DOP(3, 2, 0, 55)  DOP(4, 2, 2, 56)  DOP(5, 2, 1, 83)  DOP(6, 2, 3, 86)
  }
  { // l2=3: paths 3,9,15,16,21,22
    float h0[7], h1[7], w0[6], w1[6];
#pragma unroll
    for (int m = 0; m < 7; ++m) {
      h0[m] = Hn[(9 + m) * 128]; h1[m] = Hn[(9 + m) * 128 + 1];
    }
    const int pid[6] = {3, 9, 15, 16, 21, 22};
#pragma unroll
    for (int i = 0; i < 6; ++i) {
      w0[i] = Wn[pid[i] * 128]; w1[i] = Wn[pid[i] * 128 + 1];
    }
#pragma unroll
    for (int m = 0; m < 7; ++m) { PIN(h0[m]) PIN(h1[m]) }
#pragma unroll
    for (int i = 0; i < 6; ++i) { PIN(w0[i]) PIN(w1[i]) }
    DOP(0, 3, 3, 9)   DOP(1, 3, 2, 35)  DOP(2, 3, 1, 61)
    DOP(3, 3, 3, 64)  DOP(4, 3, 0, 93)  DOP(5, 3, 2, 94)
  }
#undef DOP
#undef PIN

#pragma unroll
  for (int c = 0; c < YD; ++c) {
    __builtin_nontemporal_store(acc0[c], &On[c * 128]);
    __builtin_nontemporal_store(acc1[c], &On[c * 128 + 1]);
  }
}

extern "C" void kernel_launch(void* const* d_in, const int* in_sizes, int n_in,
                              void* d_out, int out_size, void* d_ws, size_t ws_size,
                              hipStream_t stream) {
  const float* Y  = (const float*)d_in[0];
  const float* H  = (const float*)d_in[1];
  const float* W  = (const float*)d_in[2];
  const float* CG = (const float*)d_in[3];
  float* O = (float*)d_out;

  const int n_edges = in_sizes[0] / YD;        // 16384
  etp_kernel<<<n_edges / EPB, BS, 0, stream>>>(Y, H, W, CG, O);
}

// Round 18
// 97.697 us; speedup vs baseline: 4.5401x; 4.5401x over previous
//
#include <hip/hip_runtime.h>

// etp: out[n, coff(l3)+m3, u] = sum_p sum_{m1,m2} cg_p[m1,m2,m3] * Y[n, yoff(l1)+m1]
//                               * H[n, coff(l2)+m2, u] * W[n, p, u]
// N=16384 edges, 16 ch (l=0..3, dims 1,3,5,7), MUL=128.
//
// R17 = R13 champion skeleton (scalar u, 128 thr/edge, 2 edges/block,
// upfront h+w burst with sequential pins, launch_bounds(256,6), nt stores)
// with a PACKED B layout: each path stored flat (m3*d2+m2), padded to
// 4-float alignment, so every ds_read_b128 delivers 4 consumable values.
// LDS issues/wave: 158 -> 121 (R13's padded-8 rows burned a b128 per row;
// d2=1 paths used 16 reads for 16 floats). R13's 95us closes exactly with
// the LDS-issue model (32768 waves x 158 x ~11.6cyc / 256CU = 98us); this
// attacks that pipe directly. Per-path consume keeps s[d3<=7]+one chunk
// live -> no register pressure growth.

#define BS 256
#define EPB 2     // edges per block
#define TPE 128   // threads per edge
#define YD 16
#define HD 2048
#define WD 2944
#define NP 23
#define BTOT 484  // packed B floats per edge (1936 B, 16B-aligned)

typedef float f4 __attribute__((ext_vector_type(4)));

__host__ __device__ constexpr int coff(int l) {
  return l == 0 ? 0 : (l == 1 ? 1 : (l == 2 ? 4 : 9));
}

// X(p, l1, l2, l3, cg_offset, flat_base)
#define FOR_PATHS(X) \
  X(0, 0,0,0,    0,   0) \
  X(1, 0,1,1,    1,  24) \
  X(2, 0,2,2,   10, 108) \
  X(3, 0,3,3,   35, 276) \
  X(4, 1,0,1,   84,   4) \
  X(5, 1,1,0,   93,  36) \
  X(6, 1,1,2,  102,  40) \
  X(7, 1,2,1,  147, 136) \
  X(8, 1,2,3,  192, 152) \
  X(9, 1,3,2,  297, 328) \
  X(10,2,0,2,  402,   8) \
  X(11,2,1,1,  427,  56) \
  X(12,2,1,3,  472,  68) \
  X(13,2,2,0,  577, 188) \
  X(14,2,2,2,  602, 196) \
  X(15,2,3,1,  727, 364) \
  X(16,2,3,3,  832, 388) \
  X(17,3,0,3, 1077,  16) \
  X(18,3,1,2, 1126,  92) \
  X(19,3,2,1, 1231, 224) \
  X(20,3,2,3, 1336, 240) \
  X(21,3,3,0, 1581, 440) \
  X(22,3,3,2, 1630, 448)

// Consume one path: B flat at Bg[BO..BO+D2*D3), chunked b128 reads,
// compile-time (m3,m2) mapping. Live: s[D3] + one f4 chunk.
template <int D2, int D3, int BO, int C3>
__device__ __forceinline__ void dopath(const float* __restrict__ Bg,
                                       const float* __restrict__ hh,
                                       float wv, float (&acc)[YD]) {
  float s[D3];
#pragma unroll
  for (int m3 = 0; m3 < D3; ++m3) s[m3] = 0.f;
  f4 c;
#pragma unroll
  for (int f = 0; f < D2 * D3; ++f) {
    if ((f & 3) == 0) c = *(const f4*)(Bg + BO + f);
    s[f / D2] += c[f & 3] * hh[f % D2];
  }
#pragma unroll
  for (int m3 = 0; m3 < D3; ++m3) acc[C3 + m3] += s[m3] * wv;
}

__global__ __launch_bounds__(BS, 6) void etp_kernel(
    const float* __restrict__ Y, const float* __restrict__ H,
    const float* __restrict__ W, const float* __restrict__ CG,
    float* __restrict__ O) {
  const int g = threadIdx.x >> 7;    // edge within block
  const int u = threadIdx.x & 127;   // u index
  const size_t n = (size_t)blockIdx.x * EPB + g;

  __shared__ __align__(16) float Bsm[EPB][BTOT];  // 3872 B
  __shared__ float ysm[EPB][YD];

  { const int t = threadIdx.x;
    if (t < EPB * YD) {
      const int e = t >> 4, c = t & 15;
      ysm[e][c] = Y[(size_t)(blockIdx.x * EPB + e) * YD + c];
    } }
  __syncthreads();

  // Phase 1: B flat-packed: lane u (= m3*d2+m2 row-major) writes B[BO+u].
#define BUILD(P, L1, L2, L3, CGO, BO) { \
    constexpr int d1 = 2*(L1)+1, d2 = 2*(L2)+1, d3 = 2*(L3)+1; \
    if (u < d2 * d3) { \
      const int m3 = u / d2, m2 = u - m3 * d2; \
      float s = 0.f; \
      _Pragma("unroll") \
      for (int a = 0; a < d1; ++a) \
        s += CG[(CGO) + (a * d2 + m2) * d3 + m3] * ysm[g][coff(L1) + a]; \
      Bsm[g][(BO) + u] = s; \
    } }
  FOR_PATHS(BUILD)
#undef BUILD
  __syncthreads();

  // Phase 2: R13 discipline — one burst of all 39 loads, pinned, then
  // pure reg/LDS compute via packed-chunk dopath.
  const float* __restrict__ Hn = H + n * HD + u;
  const float* __restrict__ Wn = W + n * WD + u;
  float* __restrict__ On = O + n * HD + u;
  const float* __restrict__ Bg = &Bsm[g][0];

  float h[YD];
#pragma unroll
  for (int c = 0; c < YD; ++c) h[c] = Hn[c * TPE];
  float w[NP];
#pragma unroll
  for (int p = 0; p < NP; ++p) w[p] = Wn[p * TPE];
#pragma unroll
  for (int c = 0; c < YD; ++c) asm volatile("" : "+v"(h[c]));
#pragma unroll
  for (int p = 0; p < NP; ++p) asm volatile("" : "+v"(w[p]));

  float acc[YD];
#pragma unroll
  for (int c = 0; c < YD; ++c) acc[c] = 0.f;

#define DOP(P, L1, L2, L3, CGO, BO) \
  dopath<2*(L2)+1, 2*(L3)+1, BO, coff(L3)>(Bg, &h[coff(L2)], w[P], acc);
  FOR_PATHS(DOP)
#undef DOP

#pragma unroll
  for (int c = 0; c < YD; ++c)
    __builtin_nontemporal_store(acc[c], &On[c * TPE]);
}

extern "C" void kernel_launch(void* const* d_in, const int* in_sizes, int n_in,
                              void* d_out, int out_size, void* d_ws, size_t ws_size,
                              hipStream_t stream) {
  const float* Y  = (const float*)d_in[0];
  const float* H  = (const float*)d_in[1];
  const float* W  = (const float*)d_in[2];
  const float* CG = (const float*)d_in[3];
  float* O = (float*)d_out;

  const int n_edges = in_sizes[0] / YD;        // 16384
  etp_kernel<<<n_edges / EPB, BS, 0, stream>>>(Y, H, W, CG, O);
}